// Round 6
// baseline (175.417 us; speedup 1.0000x reference)
//
#include <hip/hip_runtime.h>

// 2-level 2D Haar DWT, phase-separated. x: (96, 512, 512) fp32.
// Block = 256 threads = one img x 16 rows x 512 cols tile.
// Phase R: linear float4 reads -> LDS (single contiguous 32KB stream/block).
// Phase C: Haar lvl1+lvl2 entirely in LDS.
// Phase W: per-subband contiguous bursts (each block tile is a contiguous
//          global range per array: 8KB for h1/v1/d1, 2KB for a2/h2/v2/d2).
// Out layout: a2,h2,v2,d2 (each 96*128*128), then h1,v1,d1 (each 96*256*256).

#define KINV 0.7071067811865476f

typedef float v4f __attribute__((ext_vector_type(4)));
typedef float v2f __attribute__((ext_vector_type(2)));

__global__ __launch_bounds__(256) void haar2_phase_kernel(
    const float* __restrict__ x, float* __restrict__ out, int nimg)
{
    __shared__ float in_lds[16][512];    // 32 KB
    __shared__ float l1[3][8][256];      // 24 KB  (h1,v1,d1 tiles)
    __shared__ float l2[4][4][128];      //  8 KB  (a2,h2,v2,d2 tiles)

    const int t   = threadIdx.x;
    const int bid = blockIdx.x;
    const int by  = bid & 31;            // 32 row-blocks of 16 input rows
    const int img = bid >> 5;

    // ---- Phase R: 8 independent linear 1KB/wave bursts -> LDS ----
    {
        const float* src = x + (size_t)img * (512 * 512) + (size_t)by * 16 * 512;
        v4f r[8];
        #pragma unroll
        for (int k = 0; k < 8; ++k)
            r[k] = *reinterpret_cast<const v4f*>(src + (size_t)(k * 256 + t) * 4);
        #pragma unroll
        for (int k = 0; k < 8; ++k)
            *reinterpret_cast<v4f*>(&in_lds[0][0] + (k * 256 + t) * 4) = r[k];
    }
    __syncthreads();

    // ---- Phase C: Haar math in LDS ----
    const int cx = t & 127;              // col-group: cols 4cx..4cx+3
    const int ry = t >> 7;               // 0..1: row-pair group
    float aa[4][2];                      // a1 values: 4 row-pairs x 2 cols
    #pragma unroll
    for (int i = 0; i < 4; ++i) {
        const int rp = ry * 4 + i;       // row-pair 0..7 -> input rows 2rp,2rp+1
        v4f top = *reinterpret_cast<const v4f*>(&in_lds[2 * rp    ][cx * 4]);
        v4f bot = *reinterpret_cast<const v4f*>(&in_lds[2 * rp + 1][cx * 4]);
        // exact reference op order: along W first, then along H
        const float sA0 = (top.x + top.y) * KINV, dA0 = (top.x - top.y) * KINV;
        const float sB0 = (bot.x + bot.y) * KINV, dB0 = (bot.x - bot.y) * KINV;
        const float sA1 = (top.z + top.w) * KINV, dA1 = (top.z - top.w) * KINV;
        const float sB1 = (bot.z + bot.w) * KINV, dB1 = (bot.z - bot.w) * KINV;
        aa[i][0] = (sA0 + sB0) * KINV;
        aa[i][1] = (sA1 + sB1) * KINV;
        const float da0 = (sA0 - sB0) * KINV, da1 = (sA1 - sB1) * KINV;  // cH1
        const float ad0 = (dA0 + dB0) * KINV, ad1 = (dA1 + dB1) * KINV;  // cV1
        const float dd0 = (dA0 - dB0) * KINV, dd1 = (dA1 - dB1) * KINV;  // cD1
        *reinterpret_cast<v2f*>(&l1[0][rp][cx * 2]) = (v2f){da0, da1};
        *reinterpret_cast<v2f*>(&l1[1][rp][cx * 2]) = (v2f){ad0, ad1};
        *reinterpret_cast<v2f*>(&l1[2][rp][cx * 2]) = (v2f){dd0, dd1};
    }
    #pragma unroll
    for (int jj = 0; jj < 2; ++jj) {
        const int i0 = 2 * jj;
        const float s0 = (aa[i0][0]     + aa[i0][1])     * KINV;
        const float d0 = (aa[i0][0]     - aa[i0][1])     * KINV;
        const float s1 = (aa[i0 + 1][0] + aa[i0 + 1][1]) * KINV;
        const float d1 = (aa[i0 + 1][0] - aa[i0 + 1][1]) * KINV;
        const int lr = 2 * ry + jj;      // l2 row 0..3
        l2[0][lr][cx] = (s0 + s1) * KINV;   // a2
        l2[1][lr][cx] = (s0 - s1) * KINV;   // h2
        l2[2][lr][cx] = (d0 + d1) * KINV;   // v2
        l2[3][lr][cx] = (d0 - d1) * KINV;   // d2
    }
    __syncthreads();

    // ---- Phase W: contiguous per-array streams ----
    const size_t n2 = (size_t)nimg * 128 * 128;
    const size_t n1 = (size_t)nimg * 256 * 256;

    // h1/v1/d1: block tile = rows 8by..8by+7 x 256 cols = contiguous 2048 floats.
    {
        const size_t tile1 = (size_t)img * 256 * 256 + (size_t)by * 8 * 256;
        float* bases[3] = { out + 4 * n2 + tile1,
                            out + 4 * n2 + n1 + tile1,
                            out + 4 * n2 + 2 * n1 + tile1 };
        #pragma unroll
        for (int arr = 0; arr < 3; ++arr) {
            #pragma unroll
            for (int r = 0; r < 2; ++r) {
                const int idx = r * 256 + t;    // float4 index 0..511
                v4f v = *reinterpret_cast<const v4f*>(&l1[arr][0][0] + idx * 4);
                *reinterpret_cast<v4f*>(bases[arr] + (size_t)idx * 4) = v;
            }
        }
    }
    // a2/h2/v2/d2: block tile = rows 4by..4by+3 x 128 cols = contiguous 512 floats.
    {
        const size_t tile2 = (size_t)img * 128 * 128 + (size_t)by * 4 * 128;
        #pragma unroll
        for (int r = 0; r < 2; ++r) {
            const int idx = r * 256 + t;        // 0..511
            const int arr = idx >> 7;           // 0..3
            const int rem = idx & 127;          // float4 within 2KB tile
            v4f v = *reinterpret_cast<const v4f*>(&l2[arr][0][0] + rem * 4);
            *reinterpret_cast<v4f*>(out + (size_t)arr * n2 + tile2 + (size_t)rem * 4) = v;
        }
    }
}

extern "C" void kernel_launch(void* const* d_in, const int* in_sizes, int n_in,
                              void* d_out, int out_size, void* d_ws, size_t ws_size,
                              hipStream_t stream) {
    const float* x = (const float*)d_in[0];
    float* out = (float*)d_out;
    const int nimg = in_sizes[0] / (512 * 512);   // 96
    const int grid = nimg * 32;                   // 3072 blocks
    haar2_phase_kernel<<<grid, 256, 0, stream>>>(x, out, nimg);
}